// Round 1
// baseline (225.185 us; speedup 1.0000x reference)
//
#include <hip/hip_runtime.h>

// Problem constants (from reference): codes [16,128,128,128] f32,
// segmap [16,4,1,256,256] i32, fc_w [512,128] f32, fc_b [512] f32.
// Nearest 256->128 resize == sample at (2y, 2x) exactly.
#define B   16
#define S   4
#define F   128
#define HW  16384   // 128*128 low-res pixels
#define HWIN 65536  // 256*256 segmap pixels
#define OUT 512

// ---------------- Kernel 0: pack segment masks + counts --------------------
// grid = B*16 blocks, 256 threads; each thread packs 4 low-res pixels into
// one uchar4 (bit s = segment-s membership) and accumulates per-seg counts.
__global__ __launch_bounds__(256) void mask_pack_kernel(
    const int* __restrict__ segmap,
    unsigned char* __restrict__ pmask,
    int* __restrict__ counts) {
    const int b   = blockIdx.x >> 4;
    const int blk = blockIdx.x & 15;
    const int t   = threadIdx.x;
    const int pbase = blk * 1024 + t * 4;        // 4 consecutive pixels, same row
    const int y = pbase >> 7;
    const int x = pbase & 127;
    const int* sm = segmap + (size_t)b * (S * HWIN);
    const int row = (2 * y) * 256 + 2 * x;

    unsigned char outb[4] = {0, 0, 0, 0};
    int cnt[S] = {0, 0, 0, 0};
#pragma unroll
    for (int s = 0; s < S; ++s) {
        const int* p = sm + s * HWIN + row;
#pragma unroll
        for (int j = 0; j < 4; ++j) {
            if (p[2 * j] != 0) { outb[j] |= (unsigned char)(1 << s); cnt[s]++; }
        }
    }
    *(uchar4*)(pmask + (size_t)b * HW + pbase) =
        make_uchar4(outb[0], outb[1], outb[2], outb[3]);

    __shared__ int sc[S];
    if (t < S) sc[t] = 0;
    __syncthreads();
#pragma unroll
    for (int s = 0; s < S; ++s)
        if (cnt[s]) atomicAdd(&sc[s], cnt[s]);
    __syncthreads();
    if (t < S) atomicAdd(&counts[b * S + t], sc[t]);
}

// ---------------- Kernel 1: masked segment sums (the 128 MiB pass) ---------
// grid = B*F = 2048 blocks, 256 threads. Block (b,f) reads the 64 KiB plane
// codes[b,f,:,:] as float4 + the 16 KiB packed mask as uchar4, keeps 4
// running sums per thread, block-reduces, writes sums[(b*S+s)*F + f].
__global__ __launch_bounds__(256) void masked_sum_kernel(
    const float* __restrict__ codes,
    const unsigned char* __restrict__ pmask,
    float* __restrict__ sums) {
    const int bf = blockIdx.x;
    const int b  = bf >> 7;
    const int f  = bf & 127;
    const int t  = threadIdx.x;
    const float4* cp = (const float4*)(codes + (size_t)bf * HW);
    const uchar4* mp = (const uchar4*)(pmask + (size_t)b * HW);

    float a0 = 0.f, a1 = 0.f, a2 = 0.f, a3 = 0.f;
#pragma unroll
    for (int i = 0; i < 16; ++i) {
        const int idx = i * 256 + t;            // float4 index, coalesced
        const float4 c = cp[idx];
        const uchar4 m = mp[idx];
#define ACC(mm, cc)                                                  \
        {                                                            \
            a0 += ((mm) & 1) ? (cc) : 0.f;                           \
            a1 += ((mm) & 2) ? (cc) : 0.f;                           \
            a2 += ((mm) & 4) ? (cc) : 0.f;                           \
            a3 += ((mm) & 8) ? (cc) : 0.f;                           \
        }
        ACC(m.x, c.x); ACC(m.y, c.y); ACC(m.z, c.z); ACC(m.w, c.w);
#undef ACC
    }
    // wave64 shuffle reduction
#pragma unroll
    for (int off = 32; off > 0; off >>= 1) {
        a0 += __shfl_down(a0, off);
        a1 += __shfl_down(a1, off);
        a2 += __shfl_down(a2, off);
        a3 += __shfl_down(a3, off);
    }
    __shared__ float part[4][S];                // [wave][s]
    const int wave = t >> 6;
    if ((t & 63) == 0) {
        part[wave][0] = a0; part[wave][1] = a1;
        part[wave][2] = a2; part[wave][3] = a3;
    }
    __syncthreads();
    if (t < S) {
        const float v = part[0][t] + part[1][t] + part[2][t] + part[3][t];
        sums[(size_t)(b * S + t) * F + f] = v;
    }
}

// ---------------- Kernel 2: feats = sums/counts; out = feats @ W^T + b -----
// grid = B*S = 64 blocks, 512 threads (one output each).
__global__ __launch_bounds__(512) void fc_kernel(
    const float* __restrict__ sums,
    const int* __restrict__ counts,
    const float* __restrict__ fc_w,
    const float* __restrict__ fc_b,
    float* __restrict__ out) {
    const int bs = blockIdx.x;
    const int t  = threadIdx.x;
    __shared__ float feats[F];
    if (t < F) {
        const int c = counts[bs];
        const float sv = sums[(size_t)bs * F + t];
        feats[t] = (c > 0) ? (sv / (float)c) : 0.f;
    }
    __syncthreads();
    const float4* w4 = (const float4*)(fc_w + (size_t)t * F);
    const float4* f4 = (const float4*)feats;
    float acc = fc_b[t];
#pragma unroll
    for (int i = 0; i < F / 4; ++i) {
        const float4 wv = w4[i];
        const float4 fv = f4[i];
        acc += fv.x * wv.x + fv.y * wv.y + fv.z * wv.z + fv.w * wv.w;
    }
    out[(size_t)bs * OUT + t] = acc;
}

extern "C" void kernel_launch(void* const* d_in, const int* in_sizes, int n_in,
                              void* d_out, int out_size, void* d_ws, size_t ws_size,
                              hipStream_t stream) {
    const float* codes  = (const float*)d_in[0];
    const int*   segmap = (const int*)d_in[1];
    const float* fc_w   = (const float*)d_in[2];
    const float* fc_b   = (const float*)d_in[3];
    float* out = (float*)d_out;

    // workspace layout: [pmask 256 KiB][counts 256 B][sums 32 KiB]
    unsigned char* pmask = (unsigned char*)d_ws;
    int*   counts = (int*)((char*)d_ws + (size_t)B * HW);
    float* sums   = (float*)((char*)d_ws + (size_t)B * HW + 256);

    hipMemsetAsync(counts, 0, B * S * sizeof(int), stream);
    mask_pack_kernel<<<B * 16, 256, 0, stream>>>(segmap, pmask, counts);
    masked_sum_kernel<<<B * F, 256, 0, stream>>>(codes, pmask, sums);
    fc_kernel<<<B * S, OUT, 0, stream>>>(sums, counts, fc_w, fc_b, out);
}

// Round 2
// 218.144 us; speedup vs baseline: 1.0323x; 1.0323x over previous
//
#include <hip/hip_runtime.h>

// Problem constants: codes [16,128,128,128] f32, segmap [16,4,1,256,256] i32,
// fc_w [512,128] f32, fc_b [512] f32.  Nearest 256->128 == sample (2y,2x).
#define B    16
#define S    4
#define F    128
#define HW   16384   // 128*128 low-res pixels
#define HWIN 65536   // 256*256 segmap pixels
#define OUT  512
#define PBLK 16      // mask_pack blocks per batch

// ---------------- Kernel 0: pack segment masks + per-block partial counts --
// grid = B*PBLK, 256 threads; thread packs 4 low-res pixels into one uchar4
// (bit s = segment-s membership). Per-block counts -> pcounts[block][s]
// (no global atomics, no memset needed).
__global__ __launch_bounds__(256) void mask_pack_kernel(
    const int* __restrict__ segmap,
    unsigned char* __restrict__ pmask,
    int* __restrict__ pcounts) {
    const int b   = blockIdx.x >> 4;
    const int t   = threadIdx.x;
    const int pbase = (blockIdx.x & 15) * 1024 + t * 4;  // 4 px, same row
    const int y = pbase >> 7;
    const int x = pbase & 127;
    const int* sm = segmap + (size_t)b * (S * HWIN);
    const int row = (2 * y) * 256 + 2 * x;   // byte offset 32-aligned -> int4 ok

    unsigned char outb[4] = {0, 0, 0, 0};
    int cnt[S];
#pragma unroll
    for (int s = 0; s < S; ++s) {
        const int4 l0 = *(const int4*)(sm + s * HWIN + row);
        const int4 l1 = *(const int4*)(sm + s * HWIN + row + 4);
        int c = 0;
        if (l0.x) { outb[0] |= (1 << s); c++; }
        if (l0.z) { outb[1] |= (1 << s); c++; }
        if (l1.x) { outb[2] |= (1 << s); c++; }
        if (l1.z) { outb[3] |= (1 << s); c++; }
        cnt[s] = c;
    }
    *(uchar4*)(pmask + (size_t)b * HW + pbase) =
        make_uchar4(outb[0], outb[1], outb[2], outb[3]);

    // block-reduce the 4 counts: wave shuffle, then LDS across 4 waves
    __shared__ int sc[4][S];
#pragma unroll
    for (int s = 0; s < S; ++s) {
#pragma unroll
        for (int off = 32; off > 0; off >>= 1)
            cnt[s] += __shfl_down(cnt[s], off);
    }
    const int wave = t >> 6;
    if ((t & 63) == 0) {
#pragma unroll
        for (int s = 0; s < S; ++s) sc[wave][s] = cnt[s];
    }
    __syncthreads();
    if (t < S)
        pcounts[blockIdx.x * S + t] = sc[0][t] + sc[1][t] + sc[2][t] + sc[3][t];
}

// ---------------- Kernel 1: masked segment sums (the 128 MiB pass) ---------
// grid = B*F = 2048 blocks, 256 threads. Block (b,f) streams the 64 KiB plane
// codes[b,f,:,:] as 2x float4/iter + packed mask as uchar4; 4 running sums.
__global__ __launch_bounds__(256) void masked_sum_kernel(
    const float* __restrict__ codes,
    const unsigned char* __restrict__ pmask,
    float* __restrict__ sums) {
    const int bf = blockIdx.x;
    const int b  = bf >> 7;
    const int t  = threadIdx.x;
    const float4* cp = (const float4*)(codes + (size_t)bf * HW);
    const uchar4* mp = (const uchar4*)(pmask + (size_t)b * HW);

    float a0 = 0.f, a1 = 0.f, a2 = 0.f, a3 = 0.f;
#pragma unroll
    for (int i = 0; i < 8; ++i) {
        const int idx = i * 512 + t;
        const float4 c0 = cp[idx];
        const float4 c1 = cp[idx + 256];
        const uchar4 m0 = mp[idx];
        const uchar4 m1 = mp[idx + 256];
#define ACC(mm, cc)                                \
        {                                          \
            a0 += ((mm) & 1) ? (cc) : 0.f;         \
            a1 += ((mm) & 2) ? (cc) : 0.f;         \
            a2 += ((mm) & 4) ? (cc) : 0.f;         \
            a3 += ((mm) & 8) ? (cc) : 0.f;         \
        }
        ACC(m0.x, c0.x); ACC(m0.y, c0.y); ACC(m0.z, c0.z); ACC(m0.w, c0.w);
        ACC(m1.x, c1.x); ACC(m1.y, c1.y); ACC(m1.z, c1.z); ACC(m1.w, c1.w);
#undef ACC
    }
#pragma unroll
    for (int off = 32; off > 0; off >>= 1) {
        a0 += __shfl_down(a0, off);
        a1 += __shfl_down(a1, off);
        a2 += __shfl_down(a2, off);
        a3 += __shfl_down(a3, off);
    }
    __shared__ float part[4][S];
    const int wave = t >> 6;
    if ((t & 63) == 0) {
        part[wave][0] = a0; part[wave][1] = a1;
        part[wave][2] = a2; part[wave][3] = a3;
    }
    __syncthreads();
    if (t < S) {
        const int f = bf & 127;
        sums[(size_t)(b * S + t) * F + f] =
            part[0][t] + part[1][t] + part[2][t] + part[3][t];
    }
}

// ---------------- Kernel 2: counts finalize + feats @ W^T + b --------------
// grid = B*S = 64 blocks, 512 threads (one output element each).
__global__ __launch_bounds__(512) void fc_kernel(
    const float* __restrict__ sums,
    const int* __restrict__ pcounts,
    const float* __restrict__ fc_w,
    const float* __restrict__ fc_b,
    float* __restrict__ out) {
    const int bs = blockIdx.x;          // = b*S + s
    const int b  = bs >> 2;
    const int s  = bs & 3;
    const int t  = threadIdx.x;
    __shared__ float feats[F];
    __shared__ float sinv;
    if (t == 0) {
        int c = 0;
#pragma unroll
        for (int blk = 0; blk < PBLK; ++blk)
            c += pcounts[(b * PBLK + blk) * S + s];
        sinv = (c > 0) ? (1.0f / (float)c) : 0.0f;
    }
    __syncthreads();
    if (t < F) feats[t] = sums[(size_t)bs * F + t] * sinv;
    __syncthreads();

    const float4* w4 = (const float4*)(fc_w + (size_t)t * F);
    const float4* f4 = (const float4*)feats;
    float acc = fc_b[t];
#pragma unroll
    for (int i = 0; i < F / 4; ++i) {
        const float4 wv = w4[i];
        const float4 fv = f4[i];
        acc += fv.x * wv.x + fv.y * wv.y + fv.z * wv.z + fv.w * wv.w;
    }
    out[(size_t)bs * OUT + t] = acc;
}

extern "C" void kernel_launch(void* const* d_in, const int* in_sizes, int n_in,
                              void* d_out, int out_size, void* d_ws, size_t ws_size,
                              hipStream_t stream) {
    const float* codes  = (const float*)d_in[0];
    const int*   segmap = (const int*)d_in[1];
    const float* fc_w   = (const float*)d_in[2];
    const float* fc_b   = (const float*)d_in[3];
    float* out = (float*)d_out;

    // ws layout: [pmask 256 KiB][pcounts 256*4 ints][sums 64*128 f32]
    unsigned char* pmask = (unsigned char*)d_ws;
    int*   pcounts = (int*)((char*)d_ws + (size_t)B * HW);
    float* sums    = (float*)((char*)d_ws + (size_t)B * HW + B * PBLK * S * 4);

    mask_pack_kernel<<<B * PBLK, 256, 0, stream>>>(segmap, pmask, pcounts);
    masked_sum_kernel<<<B * F, 256, 0, stream>>>(codes, pmask, sums);
    fc_kernel<<<B * S, OUT, 0, stream>>>(sums, pcounts, fc_w, fc_b, out);
}